// Round 1
// baseline (31.557 us; speedup 1.0000x reference)
//
#include <hip/hip_runtime.h>
#include <math.h>

// Problem constants (from reference setup_inputs):
//   D=2048 (feature dim), K=4096 (neighbors), C=1000 (classes), W=4096 (rows of w)
constexpr int KN = 4096;
constexpr int DN = 2048;
constexpr int CN = 1000;
constexpr int WN = 4096;

__device__ __forceinline__ float waveSum(float v) {
#pragma unroll
    for (int o = 32; o > 0; o >>= 1) v += __shfl_down(v, o, 64);
    return v;
}
__device__ __forceinline__ float waveMax(float v) {
#pragma unroll
    for (int o = 32; o > 0; o >>= 1) v = fmaxf(v, __shfl_down(v, o, 64));
    return v;
}

// Stage 1 (fused): blocks [0,KN) compute d[b] = ||deep - n[b]||_2
//                  blocks [KN,2*KN) compute ce[b-KN] = logsumexp(cls[row]) - cls[row, target]
__global__ __launch_bounds__(256) void stage1_kernel(
    const float* __restrict__ deep, const float* __restrict__ nmat,
    const float* __restrict__ cls, const int* __restrict__ target,
    float* __restrict__ d_arr, float* __restrict__ ce_arr)
{
    __shared__ float red[4];
    __shared__ float bcast;
    const int b    = blockIdx.x;
    const int tid  = threadIdx.x;
    const int wave = tid >> 6;
    const int lane = tid & 63;

    if (b < KN) {
        // ---- distance row ----
        const float4* nrow = (const float4*)(nmat + (size_t)b * DN);
        const float4* df   = (const float4*)deep;
        float acc = 0.f;
#pragma unroll
        for (int c = 0; c < DN / 4 / 256; ++c) {   // 2 iters: 512 float4 / 256 threads
            const int i = tid + 256 * c;
            const float4 a = df[i];
            const float4 x = nrow[i];
            const float e0 = a.x - x.x, e1 = a.y - x.y, e2 = a.z - x.z, e3 = a.w - x.w;
            acc += e0 * e0 + e1 * e1 + e2 * e2 + e3 * e3;
        }
        acc = waveSum(acc);
        if (lane == 0) red[wave] = acc;
        __syncthreads();
        if (tid == 0) d_arr[b] = sqrtf(red[0] + red[1] + red[2] + red[3]);
    } else {
        // ---- cross-entropy row: ce = logsumexp(x) - x[target] ----
        const int row  = b - KN;
        const float* x = cls + (size_t)row * CN;
        float mx = -INFINITY;
        for (int i = tid; i < CN; i += 256) mx = fmaxf(mx, x[i]);
        mx = waveMax(mx);
        if (lane == 0) red[wave] = mx;
        __syncthreads();
        if (tid == 0) bcast = fmaxf(fmaxf(red[0], red[1]), fmaxf(red[2], red[3]));
        __syncthreads();
        mx = bcast;
        float s = 0.f;
        for (int i = tid; i < CN; i += 256) s += __expf(x[i] - mx);
        s = waveSum(s);
        __syncthreads();              // red[] reuse safety
        if (lane == 0) red[wave] = s;
        __syncthreads();
        if (tid == 0) {
            const float tot = red[0] + red[1] + red[2] + red[3];
            ce_arr[row] = mx + __logf(tot) - x[target[0]];
        }
    }
}

// Stage 2: one block per row idy of w.
//   s[k]  = -w[idy,k] * d[k]
//   row_g = sum_k exp(s-m)*ce[k] / sum_k exp(s-m)      (= dot(softmax(s), ce))
//   row_f = sum_k w[idy,k]*d[k]
__global__ __launch_bounds__(256) void stage2_kernel(
    const float* __restrict__ wmat, const float* __restrict__ d_arr,
    const float* __restrict__ ce_arr, float* __restrict__ row_g,
    float* __restrict__ row_f)
{
    __shared__ float red[3][4];
    __shared__ float bcast;
    const int b    = blockIdx.x;
    const int tid  = threadIdx.x;
    const int wave = tid >> 6;
    const int lane = tid & 63;

    const float4* wrow = (const float4*)(wmat + (size_t)b * KN);
    const float4* d4   = (const float4*)d_arr;
    const float4* c4   = (const float4*)ce_arr;

    float wd[16];   // w*d values handled by this thread
    float cv[16];   // matching ce values
    float fsum = 0.f;
    float mloc = -INFINITY;
#pragma unroll
    for (int c = 0; c < 4; ++c) {   // 1024 float4 / 256 threads
        const int i = tid + 256 * c;
        const float4 wv = wrow[i];
        const float4 dv = d4[i];
        const float4 ce = c4[i];
        wd[4 * c + 0] = wv.x * dv.x;  cv[4 * c + 0] = ce.x;
        wd[4 * c + 1] = wv.y * dv.y;  cv[4 * c + 1] = ce.y;
        wd[4 * c + 2] = wv.z * dv.z;  cv[4 * c + 2] = ce.z;
        wd[4 * c + 3] = wv.w * dv.w;  cv[4 * c + 3] = ce.w;
    }
#pragma unroll
    for (int j = 0; j < 16; ++j) {
        fsum += wd[j];
        mloc = fmaxf(mloc, -wd[j]);
    }
    // block-reduce max, broadcast
    mloc = waveMax(mloc);
    if (lane == 0) red[0][wave] = mloc;
    __syncthreads();
    if (tid == 0) bcast = fmaxf(fmaxf(red[0][0], red[0][1]), fmaxf(red[0][2], red[0][3]));
    __syncthreads();
    const float m = bcast;

    float esum = 0.f, ecsum = 0.f;
#pragma unroll
    for (int j = 0; j < 16; ++j) {
        const float e = __expf(-wd[j] - m);
        esum  += e;
        ecsum += e * cv[j];
    }
    esum  = waveSum(esum);
    ecsum = waveSum(ecsum);
    fsum  = waveSum(fsum);
    __syncthreads();   // red reuse safety
    if (lane == 0) { red[0][wave] = esum; red[1][wave] = ecsum; red[2][wave] = fsum; }
    __syncthreads();
    if (tid == 0) {
        const float te  = red[0][0] + red[0][1] + red[0][2] + red[0][3];
        const float tec = red[1][0] + red[1][1] + red[1][2] + red[1][3];
        const float tf  = red[2][0] + red[2][1] + red[2][2] + red[2][3];
        row_g[b] = tec / te;
        row_f[b] = tf;
    }
}

// Stage 3: deterministic single-block reduction of row_g + row_f -> out[0]
__global__ __launch_bounds__(256) void stage3_kernel(
    const float* __restrict__ row_g, const float* __restrict__ row_f,
    float* __restrict__ out)
{
    __shared__ float red[4];
    const int tid = threadIdx.x;
    float acc = 0.f;
#pragma unroll
    for (int c = 0; c < WN / 256; ++c) {
        const int i = tid + 256 * c;
        acc += row_g[i] + row_f[i];
    }
    acc = waveSum(acc);
    if ((tid & 63) == 0) red[tid >> 6] = acc;
    __syncthreads();
    if (tid == 0) out[0] = red[0] + red[1] + red[2] + red[3];
}

extern "C" void kernel_launch(void* const* d_in, const int* in_sizes, int n_in,
                              void* d_out, int out_size, void* d_ws, size_t ws_size,
                              hipStream_t stream) {
    const float* deep   = (const float*)d_in[0];   // [1, D]
    const float* cls    = (const float*)d_in[1];   // [K, C]
    const int*   target = (const int*)d_in[2];     // [1]
    const float* nmat   = (const float*)d_in[3];   // [K, D]
    const float* wmat   = (const float*)d_in[4];   // [W, K]

    float* ws     = (float*)d_ws;
    float* d_arr  = ws;            // [K]
    float* ce_arr = ws + KN;       // [K]
    float* row_g  = ws + 2 * KN;   // [W]
    float* row_f  = ws + 3 * KN;   // [W]

    stage1_kernel<<<2 * KN, 256, 0, stream>>>(deep, nmat, cls, target, d_arr, ce_arr);
    stage2_kernel<<<WN, 256, 0, stream>>>(wmat, d_arr, ce_arr, row_g, row_f);
    stage3_kernel<<<1, 256, 0, stream>>>(row_g, row_f, (float*)d_out);
}